// Round 3
// baseline (952.310 us; speedup 1.0000x reference)
//
#include <hip/hip_runtime.h>
#include <hip/hip_bf16.h>

// B=256, S=512, D=128, R=2048, H=0.5
#define Bn 256
#define Sn 512
#define Dn 128
#define Rn 2048
#define TB 32
#define NBLK (Sn / TB)   // 16 time-blocks
#define LDX 136          // Xs LDS row stride (bf16)
#define LDP 2052         // PX LDS row stride (bf16): 2048 + 4
#define LDI 132          // input-stage LDS row stride (fp32)
#define NT 1024          // threads per WG (16 waves)
#define NW 16

using bf16_t = __hip_bfloat16;
typedef short bf16x8 __attribute__((ext_vector_type(8)));
typedef float f32x4 __attribute__((ext_vector_type(4)));
typedef float f32x2 __attribute__((ext_vector_type(2)));

__device__ __forceinline__ f32x2 clip2(f32x2 v) {
  v = __builtin_elementwise_max(v, (f32x2)(-5.f));
  v = __builtin_elementwise_min(v, (f32x2)(5.f));
  return v;
}

// fp32 -> bf16 bits, round-to-nearest-even (values finite/clamped here).
__device__ __forceinline__ unsigned bf16rne(float f) {
  const unsigned u = __float_as_uint(f);
  return (u + 0x7fffu + ((u >> 16) & 1u)) >> 16;
}
__device__ __forceinline__ unsigned pack_bf16(f32x2 v) {
  return (bf16rne(v.y) << 16) | (bf16rne(v.x) & 0xffffu);
}

// K0: weights fp32->bf16, zero loss accumulators. Grid covers exactly Rn*Dn.
__global__ __launch_bounds__(256) void k_prep(const float* __restrict__ Wp,
                                              const float* __restrict__ Wr,
                                              bf16_t* __restrict__ Wp_b,
                                              bf16_t* __restrict__ Wr_b,
                                              float* __restrict__ losses) {
  const int i = blockIdx.x * 256 + threadIdx.x;
  Wp_b[i] = __float2bfloat16(Wp[i]);
  Wr_b[i] = __float2bfloat16(Wr[i]);
  if (i == 0) { losses[0] = 0.f; losses[1] = 0.f; }
}

// Fused pipeline, full-R per workgroup: 256 WGs (one per batch), 1024 threads.
// LDS ~148.4 KB -> 1 WG/CU, 16 waves. No global atomics on preds, no combine.
__global__ __launch_bounds__(1024, 4) void k_fused(
    const float* __restrict__ inp,
    const float* __restrict__ om_i, const float* __restrict__ ga_i,
    const float* __restrict__ al_i,
    const bf16_t* __restrict__ Wp, const float* __restrict__ bp,
    const float* __restrict__ omr, const float* __restrict__ gar,
    const float* __restrict__ alr,
    const float* __restrict__ omo, const float* __restrict__ gao,
    const float* __restrict__ alo,
    const bf16_t* __restrict__ Wr, const float* __restrict__ br,
    float* __restrict__ preds, float* __restrict__ losses) {
  __shared__ bf16_t Xs[TB * LDX];     // 8.5 KB
  __shared__ bf16_t PX[TB * LDP];     // 131.3 KB (input stage / proj / x_out)
  __shared__ float bpS[Rn];           // 8 KB
  __shared__ float smi[NW], smo[NW];

  const int tid = threadIdx.x;
  const int b = blockIdx.x;
  const int wv = tid >> 6, lane = tid & 63;
  const int lr = lane & 15, lq = lane >> 4;

  // proj bias preload (once)
  for (int i = tid; i < Rn; i += NT) bpS[i] = bp[i];

  // input oscillator state (threads 0..127 own d = tid)
  float xi = 0.f, yi = 0.f, pc_in = 0.f;
  float w2i = 0.f, g2i = 0.f, ai = 0.f;
  if (tid < Dn) {
    w2i = om_i[tid] * om_i[tid];
    g2i = 2.f * fabsf(ga_i[tid]);
    ai = al_i[tid];
  }
  const float* inpb = inp + (size_t)b * Sn * Dn;

  // reservoir/output oscillator state: thread owns r = tid*2, tid*2+1 (full R).
  const int rl = tid * 2;
  f32x2 xr = (f32x2)0.f, yr = (f32x2)0.f, xo = (f32x2)0.f, yo = (f32x2)0.f;
  f32x2 w2r, g2r, arv, w2o, g2o, aov;
  {
    f32x2 t;
    t = *(const f32x2*)(omr + rl); w2r = t * t;
    t = *(const f32x2*)(gar + rl); g2r = __builtin_elementwise_abs(t) * 2.f;
    arv = *(const f32x2*)(alr + rl);
    t = *(const f32x2*)(omo + rl); w2o = t * t;
    t = *(const f32x2*)(gao + rl); g2o = __builtin_elementwise_abs(t) * 2.f;
    aov = *(const f32x2*)(alo + rl);
  }
  f32x2 pc_out2 = (f32x2)0.f;

  // Phase-D constants: wave wv owns output tile (row-tile di, col-tile dj).
  const int dj = wv & 7, di = wv >> 3, d0 = dj * 16;
  const float bco = br[d0 + lr];  // readout bias, fixed column per lane
  const bf16_t* wr_base = Wr + (size_t)(d0 + lr) * Rn + lq * 8;

  float* Is = (float*)PX;  // input staging overlay: [TB][LDI] fp32 = 16.9 KB
  const int srow = tid >> 5, sc4 = (tid & 31) * 4;

  // prologue: stage tile 0 into registers (1 f32x4 per thread = 32x128 tile)
  f32x4 stg = __builtin_nontemporal_load(
      (const f32x4*)(inpb + (size_t)srow * Dn + sc4));

  __syncthreads();  // bpS ready

  for (int blk = 0; blk < NBLK; ++blk) {
    const int t0 = blk * TB;

    // ---- Phase A0: write register-staged input tile -> Is ----
    *(f32x4*)&Is[srow * LDI + sc4] = stg;
    __syncthreads();

    // ---- Phase A: input oscillator, 32 steps (threads 0..127) ----
    if (tid < Dn) {
#pragma unroll
      for (int tt = 0; tt < TB; ++tt) {
        const float f = Is[tt * LDI + tid];
        if (t0 + tt > 0) { const float e = xi - f; pc_in += e * e; }
        const float accel = ai * f - g2i * yi - w2i * xi;
        const float xn = fminf(fmaxf(xi + 0.5f * yi, -5.f), 5.f);
        const float yn = fminf(fmaxf(yi + 0.5f * accel, -5.f), 5.f);
        Xs[tt * LDX + tid] = __float2bfloat16(xn);
        xi = xn; yi = yn;
      }
    }
    __syncthreads();  // Xs ready; Is dead -> PX writable

    // ---- Phase B: proj [32 x 2048] = Xs[32x128] @ Wp^T -> PX (bf16) ----
    {
      bf16x8 af[2][4];
#pragma unroll
      for (int i = 0; i < 2; ++i)
#pragma unroll
        for (int k = 0; k < 4; ++k)
          af[i][k] = *(const bf16x8*)&Xs[(i * 16 + lr) * LDX + k * 32 + lq * 8];

      const int lb = wv * 128;  // wave's 128 r-columns, 8 j-tiles
      const bf16_t* wp_base = Wp + (size_t)(lb + lr) * Dn + lq * 8;
      bf16x8 bf[2][4];
#pragma unroll
      for (int k = 0; k < 4; ++k) {
        bf[0][k] = *(const bf16x8*)(wp_base + (size_t)0 * 16 * Dn + k * 32);
        bf[1][k] = *(const bf16x8*)(wp_base + (size_t)1 * 16 * Dn + k * 32);
      }
      for (int j = 0; j < 8; ++j) {
        const int pb = j & 1;
        f32x4 acc[2] = {(f32x4)0.f, (f32x4)0.f};
#pragma unroll
        for (int k = 0; k < 4; ++k) {
          acc[0] = __builtin_amdgcn_mfma_f32_16x16x32_bf16(af[0][k], bf[pb][k], acc[0], 0, 0, 0);
          acc[1] = __builtin_amdgcn_mfma_f32_16x16x32_bf16(af[1][k], bf[pb][k], acc[1], 0, 0, 0);
        }
        if (j + 2 < 8) {
#pragma unroll
          for (int k = 0; k < 4; ++k)
            bf[pb][k] = *(const bf16x8*)(wp_base + (size_t)(j + 2) * 16 * Dn + k * 32);
        }
        const int cl = lb + j * 16 + lr;
        const float bv = bpS[cl];
#pragma unroll
        for (int i = 0; i < 2; ++i)
#pragma unroll
          for (int r = 0; r < 4; ++r)
            PX[(i * 16 + lq * 4 + r) * LDP + cl] = __float2bfloat16(acc[i][r] + bv);
      }
    }
    __syncthreads();

    // ---- Phase C: reservoir + output oscillators, in place in PX ----
    {
      unsigned pk = *(unsigned*)&PX[0 * LDP + rl];
      for (int tt = 0; tt < TB; ++tt) {
        unsigned pk_n = pk;
        if (tt + 1 < TB) pk_n = *(unsigned*)&PX[(tt + 1) * LDP + rl];
        f32x2 pv;
        pv.x = __uint_as_float(pk << 16);
        pv.y = __uint_as_float(pk & 0xffff0000u);
        f32x2 acr = arv * pv - g2r * yr - w2r * xr;
        f32x2 xrn = clip2(xr + yr * 0.5f);
        f32x2 yrn = clip2(yr + acr * 0.5f);
        f32x2 aco = aov * xrn - g2o * yo - w2o * xo;
        f32x2 xon = clip2(xo + yo * 0.5f);
        f32x2 yon = clip2(yo + aco * 0.5f);
        f32x2 e = xon - xrn;
        pc_out2 += e * e;
        xr = xrn; yr = yrn; xo = xon; yo = yon;
        *(unsigned*)&PX[tt * LDP + rl] = pack_bf16(xon);
        pk = pk_n;
      }
    }
    __syncthreads();

    // ---- Phase D: preds [32 x 128] = PX[32x2048] @ Wr^T + br, direct store ----
    // 16 waves x one 16x16 tile, full K=2048 per wave. Prefetch next input tile
    // under the MFMA loop so its HBM latency never meets a barrier drain.
    {
      if (blk + 1 < NBLK)
        stg = __builtin_nontemporal_load(
            (const f32x4*)(inpb + (size_t)(t0 + TB) * Dn + (size_t)srow * Dn + sc4));

      f32x4 acc[2] = {(f32x4)0.f, (f32x4)0.f};
      bf16x8 bcur = *(const bf16x8*)(wr_base);
#pragma unroll 2
      for (int k0 = 0; k0 < Rn; k0 += 32) {
        bf16x8 bnxt = bcur;
        if (k0 + 32 < Rn) bnxt = *(const bf16x8*)(wr_base + k0 + 32);
        bf16x8 a = *(const bf16x8*)&PX[(di * 16 + lr) * LDP + k0 + lq * 8];
        const int par = (k0 >> 5) & 1;
        acc[par] = __builtin_amdgcn_mfma_f32_16x16x32_bf16(a, bcur, acc[par], 0, 0, 0);
        bcur = bnxt;
      }
      float* outb = preds + (size_t)b * Sn * Dn + (size_t)t0 * Dn;
      const f32x4 s = acc[0] + acc[1];
#pragma unroll
      for (int r = 0; r < 4; ++r) {
        const int row = di * 16 + lq * 4 + r;
        __builtin_nontemporal_store(s[r] + bco, outb + (size_t)row * Dn + d0 + lr);
      }
    }
    __syncthreads();  // PX reads done before next iteration's Is overlay write
  }

  // ---- loss reduction: one atomicAdd per WG per loss ----
  float vi = pc_in;
  float vo = pc_out2.x + pc_out2.y;
#pragma unroll
  for (int o = 32; o > 0; o >>= 1) {
    vi += __shfl_down(vi, o, 64);
    vo += __shfl_down(vo, o, 64);
  }
  if (lane == 0) { smi[wv] = vi; smo[wv] = vo; }
  __syncthreads();
  if (tid == 0) {
    float si = 0.f, so = 0.f;
#pragma unroll
    for (int w = 0; w < NW; ++w) { si += smi[w]; so += smo[w]; }
    atomicAdd(losses + 0, si * (1.f / ((float)Bn * (float)Dn)));
    atomicAdd(losses + 1, so * (1.f / ((float)Bn * (float)Rn)));
  }
}

extern "C" void kernel_launch(void* const* d_in, const int* in_sizes, int n_in,
                              void* d_out, int out_size, void* d_ws, size_t ws_size,
                              hipStream_t stream) {
  const float* inputs    = (const float*)d_in[0];
  const float* omega_in  = (const float*)d_in[1];
  const float* gamma_in  = (const float*)d_in[2];
  const float* alpha_in  = (const float*)d_in[3];
  const float* W_proj    = (const float*)d_in[4];
  const float* b_proj    = (const float*)d_in[5];
  const float* omega_res = (const float*)d_in[6];
  const float* gamma_res = (const float*)d_in[7];
  const float* alpha_res = (const float*)d_in[8];
  const float* omega_out = (const float*)d_in[9];
  const float* gamma_out = (const float*)d_in[10];
  const float* alpha_out = (const float*)d_in[11];
  const float* W_read    = (const float*)d_in[12];
  const float* b_read    = (const float*)d_in[13];

  float* out = (float*)d_out;
  float* losses = out + (size_t)Bn * Sn * Dn;  // outputs: preds | pc_in | pc_out

  // ws: 1 MB — bf16 copies of the two weight matrices.
  bf16_t* Wp_b = (bf16_t*)d_ws;
  bf16_t* Wr_b = Wp_b + (size_t)Rn * Dn;

  k_prep<<<1024, 256, 0, stream>>>(W_proj, W_read, Wp_b, Wr_b, losses);
  k_fused<<<Bn, NT, 0, stream>>>(inputs, omega_in, gamma_in, alpha_in,
                                 Wp_b, b_proj,
                                 omega_res, gamma_res, alpha_res,
                                 omega_out, gamma_out, alpha_out,
                                 Wr_b, b_read, out, losses);
}